// Round 2
// baseline (788.718 us; speedup 1.0000x reference)
//
#include <hip/hip_runtime.h>
#include <hip/hip_bf16.h>
#include <stdint.h>

// QSGDLinear: out[2048,16384] = x[2048,4096] @ W^T, W[o,i] = ternary[o,i]*scales[o*32+i/128]
#define M_ROWS 2048
#define IN_F   4096
#define OUT_F  16384

#define BM 128
#define BN 128
#define BK 64

typedef __attribute__((ext_vector_type(8))) short short8;   // 8 bf16 = 4 VGPRs
typedef __attribute__((ext_vector_type(4))) float floatx4;  // MFMA acc

__device__ __forceinline__ unsigned short f32_to_bf16_rne(float f) {
    union { float f; uint32_t u; } v; v.f = f;
    uint32_t u = v.u;
    return (unsigned short)((u + 0x7FFFu + ((u >> 16) & 1u)) >> 16);
}

// ---- pass 1: x fp32 -> bf16 (8 elems/thread) ----
__global__ __launch_bounds__(256) void convert_x_kernel(
        const float* __restrict__ x, unsigned short* __restrict__ xb) {
    int t = blockIdx.x * 256 + threadIdx.x;
    const float4* p = (const float4*)(x + (size_t)t * 8);
    float4 a = p[0];
    float4 b = p[1];
    short8 o;
    o[0] = (short)f32_to_bf16_rne(a.x);
    o[1] = (short)f32_to_bf16_rne(a.y);
    o[2] = (short)f32_to_bf16_rne(a.z);
    o[3] = (short)f32_to_bf16_rne(a.w);
    o[4] = (short)f32_to_bf16_rne(b.x);
    o[5] = (short)f32_to_bf16_rne(b.y);
    o[6] = (short)f32_to_bf16_rne(b.z);
    o[7] = (short)f32_to_bf16_rne(b.w);
    *(short8*)(xb + (size_t)t * 8) = o;
}

// pack two ternary ints times scale s into one dword of 2 bf16 (truncate;
// rounding pre-added into s's bits). t*s is EXACTLY +/-s or 0 in fp32, so
// the only rounding is the one we folded into s.
__device__ __forceinline__ unsigned int pack2(int t0, int t1, float s) {
    float w0 = (float)t0 * s;
    float w1 = (float)t1 * s;
    // dst = { hi16(w1), hi16(w0) }  (w0 in low half)
    return __builtin_amdgcn_perm(__float_as_uint(w1), __float_as_uint(w0),
                                 0x07060302u);
}

// ---- fused GEMM: C = A(bf16) * (dequant(T,S))^T ----
// 256 thr = 4 waves (2x2 of 64x64). 16x16x32 bf16 MFMA, XOR-swizzled LDS.
// A staged via global_load_lds width=16; B staged via int32 loads + in-reg
// dequant + lane-contiguous ds_write_b128 (conflict-free by construction).
__global__ __launch_bounds__(256, 3) void gemm_fused_kernel(
        const unsigned short* __restrict__ A,   // [M_ROWS][IN_F] bf16 bits
        const int* __restrict__ T,              // [OUT_F][IN_F] ternary int32
        const float* __restrict__ S,            // [OUT_F*IN_F/128] scales
        float* __restrict__ C) {                // [M_ROWS][OUT_F] fp32
    __shared__ unsigned short As[BM * BK];      // 16 KB
    __shared__ unsigned short Bs[BN * BK];      // 16 KB

    const int tid  = threadIdx.x;
    const int lane = tid & 63;
    const int quad = lane >> 4;
    const int frow = lane & 15;
    const int r7   = frow & 7;
    const int w    = tid >> 6;
    const int wm   = (w & 1) * 64;
    const int wn   = (w >> 1) * 64;

    const int bm = blockIdx.x * BM;
    const int bn = blockIdx.y * BN;

    // B staging ownership, derived backwards from lane-contiguous LDS chunks:
    // thread t writes LDS chunks c = i*256 + t (i=0..3) -> row = c>>3,
    // slot = c&7 = t&7; XOR swizzle => global k-chunk jcol = (t&7) ^ (row&7),
    // invariant across i because rows differ by 32.
    const int r0   = tid >> 3;                 // 0..31
    const int jcol = (tid & 7) ^ (r0 & 7);

    floatx4 acc[4][4] = {};

    // fragment LDS element-offsets (constant over kt)
    int a_off[2][4], b_off[2][4];
#pragma unroll
    for (int ks = 0; ks < 2; ++ks) {
        const int j = ks * 4 + quad;
        const int sw = (j ^ r7) * 8;
#pragma unroll
        for (int t2 = 0; t2 < 4; ++t2) {
            a_off[ks][t2] = (wm + t2 * 16 + frow) * BK + sw;
            b_off[ks][t2] = (wn + t2 * 16 + frow) * BK + sw;
        }
    }

    for (int kt = 0; kt < IN_F; kt += BK) {
        __syncthreads();

        // ---- B: global int32 loads + scales (issued first) ----
        int4 q0[4], q1[4];
        float sc[4];
#pragma unroll
        for (int i = 0; i < 4; ++i) {
            const int row = r0 + 32 * i;
            const int* gp = T + (size_t)(bn + row) * IN_F + kt + jcol * 8;
            q0[i] = *(const int4*)gp;
            q1[i] = *(const int4*)(gp + 4);
            sc[i] = S[(size_t)(bn + row) * 32 + (kt >> 7)];
        }

        // ---- A: global_load_lds, 4 x 16B per thread, XOR swizzle ----
#pragma unroll
        for (int i = 0; i < 4; ++i) {
            const int c    = 256 * i + tid;
            const int crow = c >> 3;
            const int jg   = (c & 7) ^ (crow & 7);
            const int ub   = (256 * i + (tid & 192)) * 8;
            const unsigned short* ga =
                A + (size_t)(bm + crow) * IN_F + kt + jg * 8;
            __builtin_amdgcn_global_load_lds(
                (const __attribute__((address_space(1))) void*)ga,
                (__attribute__((address_space(3))) void*)(As + ub), 16, 0, 0);
        }

        // ---- B: dequant + conflict-free ds_write_b128 ----
#pragma unroll
        for (int i = 0; i < 4; ++i) {
            // round-half-up bf16 folded into the scale bits (s > 0 always)
            const float s = __uint_as_float(__float_as_uint(sc[i]) + 0x8000u);
            int4 o;
            o.x = (int)pack2(q0[i].x, q0[i].y, s);
            o.y = (int)pack2(q0[i].z, q0[i].w, s);
            o.z = (int)pack2(q1[i].x, q1[i].y, s);
            o.w = (int)pack2(q1[i].z, q1[i].w, s);
            *(int4*)(Bs + (size_t)(256 * i + tid) * 8) = o;
        }

        __syncthreads();

        // ---- compute: 2 k-steps x 16 MFMAs per wave ----
#pragma unroll
        for (int ks = 0; ks < 2; ++ks) {
            short8 af[4], bf[4];
#pragma unroll
            for (int t2 = 0; t2 < 4; ++t2) {
                af[t2] = *(const short8*)(As + a_off[ks][t2]);
                bf[t2] = *(const short8*)(Bs + b_off[ks][t2]);
            }
#pragma unroll
            for (int mt = 0; mt < 4; ++mt)
#pragma unroll
                for (int nt = 0; nt < 4; ++nt)
                    acc[mt][nt] = __builtin_amdgcn_mfma_f32_16x16x32_bf16(
                        af[mt], bf[nt], acc[mt][nt], 0, 0, 0);
        }
    }

    // epilogue: C/D layout col = lane&15, row = quad*4 + reg  [m89/m91]
    const int row0 = bm + wm + quad * 4;
    const int col0 = bn + wn + frow;
#pragma unroll
    for (int mt = 0; mt < 4; ++mt) {
#pragma unroll
        for (int nt = 0; nt < 4; ++nt) {
            float* cp = C + (size_t)(row0 + mt * 16) * OUT_F + (col0 + nt * 16);
#pragma unroll
            for (int r = 0; r < 4; ++r)
                cp[(size_t)r * OUT_F] = acc[mt][nt][r];
        }
    }
}

extern "C" void kernel_launch(void* const* d_in, const int* in_sizes, int n_in,
                              void* d_out, int out_size, void* d_ws, size_t ws_size,
                              hipStream_t stream) {
    const float* x    = (const float*)d_in[0];
    const int*   tern = (const int*)d_in[1];
    const float* scal = (const float*)d_in[2];
    float*       out  = (float*)d_out;

    unsigned short* xb = (unsigned short*)d_ws;   // 16.8 MB

    convert_x_kernel<<<(M_ROWS * IN_F / 8) / 256, 256, 0, stream>>>(x, xb);
    gemm_fused_kernel<<<dim3(M_ROWS / BM, OUT_F / BN), 256, 0, stream>>>(
        xb, tern, scal, out);
}

// Round 3
// 728.454 us; speedup vs baseline: 1.0827x; 1.0827x over previous
//
#include <hip/hip_runtime.h>
#include <hip/hip_bf16.h>
#include <stdint.h>

// QSGDLinear: out[2048,16384] = x[2048,4096] @ W^T, W[o,i] = ternary[o,i]*scales[o*32+i/128]
#define M_ROWS 2048
#define IN_F   4096
#define OUT_F  16384

#define BM 128
#define BN 128
#define BK 64

typedef __attribute__((ext_vector_type(8))) short short8;   // 8 bf16 = 4 VGPRs
typedef __attribute__((ext_vector_type(4))) float floatx4;  // MFMA acc

__device__ __forceinline__ unsigned int f32_to_bf16_rne(float f) {
    union { float f; uint32_t u; } v; v.f = f;
    uint32_t u = v.u;
    return (u + 0x7FFFu + ((u >> 16) & 1u)) >> 16;
}

// ---- pass 1: x fp32 -> bf16 (8 elems/thread) ----
__global__ __launch_bounds__(256) void convert_x_kernel(
        const float* __restrict__ x, unsigned short* __restrict__ xb) {
    int t = blockIdx.x * 256 + threadIdx.x;
    const float4* p = (const float4*)(x + (size_t)t * 8);
    float4 a = p[0];
    float4 b = p[1];
    short8 o;
    o[0] = (short)f32_to_bf16_rne(a.x);
    o[1] = (short)f32_to_bf16_rne(a.y);
    o[2] = (short)f32_to_bf16_rne(a.z);
    o[3] = (short)f32_to_bf16_rne(a.w);
    o[4] = (short)f32_to_bf16_rne(b.x);
    o[5] = (short)f32_to_bf16_rne(b.y);
    o[6] = (short)f32_to_bf16_rne(b.z);
    o[7] = (short)f32_to_bf16_rne(b.w);
    *(short8*)(xb + (size_t)t * 8) = o;
}

// ---- pass 2: ternary int32 -> 2-bit codes (bit0 = nonzero, bit1 = sign) ----
// 16 elems -> one u32; elem e of the 16 sits at bits [2e+1:2e].
__device__ __forceinline__ unsigned int code2(int t) {
    return (unsigned int)((t & 1) | ((t >> 30) & 2));
}
__global__ __launch_bounds__(256) void pack_t_kernel(
        const int* __restrict__ tern, unsigned int* __restrict__ tp) {
    int g = blockIdx.x * 256 + threadIdx.x;           // 16 elems per thread
    const int4* p = (const int4*)(tern + (size_t)g * 16);
    unsigned int c = 0;
#pragma unroll
    for (int q = 0; q < 4; ++q) {
        int4 v = p[q];
        c |= code2(v.x) << (8 * q + 0);
        c |= code2(v.y) << (8 * q + 2);
        c |= code2(v.z) << (8 * q + 4);
        c |= code2(v.w) << (8 * q + 6);
    }
    tp[g] = c;
}

// unpack one nibble (2 elems) -> one dword of 2 bf16.
// b: bit0 nz0, bit1 sg0, bit2 nz1, bit3 sg1. sbb = bf16(s) replicated in both halves.
__device__ __forceinline__ unsigned int dq2(unsigned int b4, unsigned int sbb) {
    unsigned int b = b4 & 0xFu;
    unsigned int p = (b | (b << 14)) & 0x10001u;          // nz bits at 0 and 16
    unsigned int m = p * 0xFFFFu;                          // u24 mul: 16-bit masks
    return (m & sbb) | ((b & 2u) << 14) | ((b & 8u) << 28);
}

// ---- fused GEMM: C = A(bf16) * (dequant(2bit,S))^T ----
// 256 thr = 4 waves (2x2 of 64x64), 16x16x32 bf16 MFMA, XOR-swizzled LDS.
// A staged via global_load_lds width=16; B staged from 2-bit codes (16.8 MB
// total, L2/L3-resident) + in-register dequant + lane-contiguous ds_write_b128.
__global__ __launch_bounds__(256, 3) void gemm_fused_kernel(
        const unsigned short* __restrict__ A,    // [M_ROWS][IN_F] bf16 bits
        const unsigned short* __restrict__ T2,   // packed codes, u16 = 8 elems
        const float* __restrict__ S,             // [OUT_F*IN_F/128] scales
        float* __restrict__ C) {                 // [M_ROWS][OUT_F] fp32
    __shared__ unsigned short As[BM * BK];       // 16 KB
    __shared__ unsigned short Bs[BN * BK];       // 16 KB

    const int tid  = threadIdx.x;
    const int lane = tid & 63;
    const int quad = lane >> 4;
    const int frow = lane & 15;
    const int r7   = frow & 7;
    const int w    = tid >> 6;
    const int wm   = (w & 1) * 64;
    const int wn   = (w >> 1) * 64;

    const int bm = blockIdx.x * BM;
    const int bn = blockIdx.y * BN;

    // B staging ownership (backwards from lane-contiguous LDS chunks):
    // thread t writes chunks c = i*256 + t -> row = 32i + (t>>3), slot = t&7,
    // global k-chunk jcol = (t&7) ^ ((t>>3)&7), invariant over i.
    const int r0   = tid >> 3;                  // 0..31
    const int jcol = (tid & 7) ^ (r0 & 7);

    floatx4 acc[4][4] = {};

    int a_off[2][4], b_off[2][4];
#pragma unroll
    for (int ks = 0; ks < 2; ++ks) {
        const int j = ks * 4 + quad;
        const int sw = (j ^ r7) * 8;
#pragma unroll
        for (int t2 = 0; t2 < 4; ++t2) {
            a_off[ks][t2] = (wm + t2 * 16 + frow) * BK + sw;
            b_off[ks][t2] = (wn + t2 * 16 + frow) * BK + sw;
        }
    }

    unsigned int sbb[4];   // bf16(scale) replicated to both halves, per row

    for (int kt = 0; kt < IN_F; kt += BK) {
        __syncthreads();

        // ---- B: 2-bit code loads (u16 = this thread's 8-elem chunk per row) ----
        unsigned int cw[4];
#pragma unroll
        for (int i = 0; i < 4; ++i) {
            const int row = bn + r0 + 32 * i;
            cw[i] = T2[(size_t)row * (IN_F / 8) + (kt >> 3) + jcol];
        }
        if ((kt & 127) == 0) {   // scale group changes every 2 k-tiles
#pragma unroll
            for (int i = 0; i < 4; ++i) {
                const int row = bn + r0 + 32 * i;
                const float s = S[(size_t)row * (IN_F / 128) + (kt >> 7)];
                sbb[i] = f32_to_bf16_rne(s) * 0x10001u;
            }
        }

        // ---- A: global_load_lds, 4 x 16B per thread, XOR swizzle ----
#pragma unroll
        for (int i = 0; i < 4; ++i) {
            const int c    = 256 * i + tid;
            const int crow = c >> 3;
            const int jg   = (c & 7) ^ (crow & 7);
            const int ub   = (256 * i + (tid & 192)) * 8;
            const unsigned short* ga =
                A + (size_t)(bm + crow) * IN_F + kt + jg * 8;
            __builtin_amdgcn_global_load_lds(
                (const __attribute__((address_space(1))) void*)ga,
                (__attribute__((address_space(3))) void*)(As + ub), 16, 0, 0);
        }

        // ---- B: unpack + conflict-free ds_write_b128 ----
#pragma unroll
        for (int i = 0; i < 4; ++i) {
            const unsigned int c = cw[i], sb2 = sbb[i];
            int4 o;
            o.x = (int)dq2(c,       sb2);
            o.y = (int)dq2(c >> 4,  sb2);
            o.z = (int)dq2(c >> 8,  sb2);
            o.w = (int)dq2(c >> 12, sb2);
            *(int4*)(Bs + (size_t)(256 * i + tid) * 8) = o;
        }

        __syncthreads();

        // ---- compute: 2 k-steps x 16 MFMAs per wave ----
#pragma unroll
        for (int ks = 0; ks < 2; ++ks) {
            short8 af[4], bf[4];
#pragma unroll
            for (int t2 = 0; t2 < 4; ++t2) {
                af[t2] = *(const short8*)(As + a_off[ks][t2]);
                bf[t2] = *(const short8*)(Bs + b_off[ks][t2]);
            }
#pragma unroll
            for (int mt = 0; mt < 4; ++mt)
#pragma unroll
                for (int nt = 0; nt < 4; ++nt)
                    acc[mt][nt] = __builtin_amdgcn_mfma_f32_16x16x32_bf16(
                        af[mt], bf[nt], acc[mt][nt], 0, 0, 0);
        }
    }

    // epilogue: C/D layout col = lane&15, row = quad*4 + reg  [m89/m91]
    const int row0 = bm + wm + quad * 4;
    const int col0 = bn + wn + frow;
#pragma unroll
    for (int mt = 0; mt < 4; ++mt) {
#pragma unroll
        for (int nt = 0; nt < 4; ++nt) {
            float* cp = C + (size_t)(row0 + mt * 16) * OUT_F + (col0 + nt * 16);
#pragma unroll
            for (int r = 0; r < 4; ++r)
                cp[(size_t)r * OUT_F] = acc[mt][nt][r];
        }
    }
}

extern "C" void kernel_launch(void* const* d_in, const int* in_sizes, int n_in,
                              void* d_out, int out_size, void* d_ws, size_t ws_size,
                              hipStream_t stream) {
    const float* x    = (const float*)d_in[0];
    const int*   tern = (const int*)d_in[1];
    const float* scal = (const float*)d_in[2];
    float*       out  = (float*)d_out;

    unsigned short* xb = (unsigned short*)d_ws;                   // 16.8 MB
    unsigned int*   tp = (unsigned int*)(xb + (size_t)M_ROWS * IN_F); // 16.8 MB

    convert_x_kernel<<<(M_ROWS * IN_F / 8) / 256, 256, 0, stream>>>(x, xb);
    pack_t_kernel<<<((size_t)OUT_F * IN_F / 16) / 256, 256, 0, stream>>>(tern, tp);
    gemm_fused_kernel<<<dim3(M_ROWS / BM, OUT_F / BN), 256, 0, stream>>>(
        xb, (const unsigned short*)tp, scal, out);
}